// Round 1
// baseline (186.901 us; speedup 1.0000x reference)
//
#include <hip/hip_runtime.h>

// Problem constants
#define T_SEQ 2048
#define C_DIM 1024
#define H_NUM 16
#define H_D   64
#define B_NUM 4
#define M_ROWS 8192   // B*T

typedef __attribute__((ext_vector_type(4))) float f32x4;
typedef __attribute__((ext_vector_type(8))) short bf16x8;   // 8 bf16 = 4 VGPRs (per guide §3)

__device__ __forceinline__ unsigned short f2bf(float f) {
  union { float f; unsigned int u; } a;
  a.f = f;
  unsigned int u = a.u;
  u += 0x7fffu + ((u >> 16) & 1u);   // RNE
  return (unsigned short)(u >> 16);
}

__device__ __forceinline__ unsigned int fbits(float f) {
  union { float f; unsigned int u; } a; a.f = f; return a.u;
}

// pack the high halves (bf16-truncate) of two f32 into one u32: {hi(b), hi(a)}
__device__ __forceinline__ unsigned int pack_hi(float a, float b) {
#if __has_builtin(__builtin_amdgcn_perm)
  return __builtin_amdgcn_perm(fbits(b), fbits(a), 0x07060302u);  // 1 VALU op
#else
  return (fbits(b) & 0xffff0000u) | (fbits(a) >> 16);
#endif
}

// async global->LDS, 16B per lane; LDS dest = wave-uniform base + lane*16
__device__ __forceinline__ void gload_lds16(const unsigned short* g, unsigned short* l) {
  __builtin_amdgcn_global_load_lds(
      (const __attribute__((address_space(1))) unsigned int*)g,
      (__attribute__((address_space(3))) unsigned int*)l, 16, 0, 0);
}

// ---------------------------------------------------------------- fused cast fp32 -> bf16
__global__ __launch_bounds__(256) void cast_all_kernel(const float* __restrict__ x,
                                                       const float* __restrict__ wa,
                                                       const float* __restrict__ wp,
                                                       unsigned short* __restrict__ xb,
                                                       unsigned short* __restrict__ wab,
                                                       unsigned short* __restrict__ wpb) {
  int i = blockIdx.x * 256 + threadIdx.x;
  const float* src;
  unsigned short* dst;
  int off;
  if (i < 2097152) {           // x: 8192*1024/4
    src = x; dst = xb; off = i;
  } else if (i < 2883584) {    // w_attn: 3072*1024/4
    src = wa; dst = wab; off = i - 2097152;
  } else {                     // w_proj: 1024*1024/4
    src = wp; dst = wpb; off = i - 2883584;
  }
  float4 v = reinterpret_cast<const float4*>(src)[off];
  ushort4 o;
  o.x = f2bf(v.x); o.y = f2bf(v.y); o.z = f2bf(v.z); o.w = f2bf(v.w);
  reinterpret_cast<ushort4*>(dst)[off] = o;
}

// ---------------------------------------------------------------- GEMM  C = A * B^T
// Round 1 change: replace the m97 single-buffer {stage -> vmcnt(0)-drain ->
// compute} structure (measured MfmaUtil 21%, nothing saturated -> drain-
// latency-bound) with the attn kernel's PROVEN counted-vmcnt 3-buffer
// pipeline (T3+T4): stage tile kt+2 while computing kt, wait vmcnt(4) (one
// stage = 4 loads in flight), ONE barrier per iteration. BK=32 so 3 stage
// buffers = 48KB LDS -> 3 blocks/CU (launch_bounds(256,3)) for TLP on top.
//
// LDS layout per buffer: A 8KB | B 8KB. Physical rows of 128B hold TWO
// logical 64B rows; slot8 = ((r&1)<<2 | s4) ^ (physrow&7). LDS dest stays
// linear for global_load_lds (rule #21); the swizzle is applied to the
// global SOURCE address at stage and to the ds_read address. Per 8-lane
// phase each of the 8 16B slots is hit exactly once -> conflict-free
// (same property as the round-0 kernel, verified 0 conflicts).
//
// EPI 0: QKV epilogue -> q*0.125*log2e, k [BH,T,D], v^T [BH,D,T'] k-permuted
// EPI 1: plain fp32 row-major [M,1024] output   (epilogues unchanged)
template <int EPI>
__global__ __launch_bounds__(256, 3) void gemm_bt_kernel(
    const unsigned short* __restrict__ A,
    const unsigned short* __restrict__ Bw,
    unsigned short* __restrict__ q_ws,
    unsigned short* __restrict__ k_ws,
    unsigned short* __restrict__ v_ws,
    float* __restrict__ outf) {
  constexpr int NN = (EPI == 0) ? 3072 : 1024;
  constexpr int KK = 1024;
  constexpr int NBC = NN / 128;
  constexpr int KT = KK / 32;          // 32 K-steps of 32

  __shared__ __align__(16) unsigned short lds[3][8192];   // 3 x (A 8KB | B 8KB) = 48KB

  const int bid = blockIdx.x;
  const int rb = bid / NBC, cb = bid % NBC;
  const int t = threadIdx.x;
  const int w = t >> 6, l = t & 63;
  const int wr = w >> 1, wc = w & 1;
  const int lq = l & 15, lg = l >> 4;

  const size_t a_base = (size_t)(rb * 128) * KK;
  const size_t b_base = (size_t)(cb * 128) * KK;

  // staging chunk c in [0,512): LDS dest linear at c*16B (phys row p=c>>3,
  // slot8=c&7). Source = inverse swizzle: sl8' = (c&7)^(p&7);
  // logical row r = (p<<1)|(sl8'>>2), k-slot s = sl8'&3.
  const unsigned short* srcA[2];
  const unsigned short* srcB[2];
#pragma unroll
  for (int i = 0; i < 2; ++i) {
    int c = t + 256 * i;
    int p = c >> 3;
    int sp = (c & 7) ^ (p & 7);
    int r = (p << 1) | (sp >> 2);
    int s = sp & 3;
    srcA[i] = A + a_base + (size_t)r * KK + s * 8;
    srcB[i] = Bw + b_base + (size_t)r * KK + s * 8;
  }

  // ds_read offsets (loop-invariant): logical row R, k-slot lg ->
  // phys p = R>>1, slot8 = ((R&1)<<2 | lg) ^ (p&7)
  int offA[4], offB[4];
#pragma unroll
  for (int i = 0; i < 4; ++i) {
    int R = wr * 64 + i * 16 + lq;
    int p = R >> 1;
    int sl = (((R & 1) << 2) | lg) ^ (p & 7);
    offA[i] = p * 64 + sl * 8;
  }
#pragma unroll
  for (int j = 0; j < 4; ++j) {
    int R = wc * 64 + j * 16 + lq;
    int p = R >> 1;
    int sl = (((R & 1) << 2) | lg) ^ (p & 7);
    offB[j] = 4096 + p * 64 + sl * 8;
  }

  unsigned short* bA = &lds[0][0];
  unsigned short* bB = &lds[1][0];
  unsigned short* bC = &lds[2][0];

#define GSTAGE(KT_, DST)                                                    \
  { _Pragma("unroll")                                                       \
    for (int i = 0; i < 2; ++i) {                                           \
      gload_lds16(srcA[i] + (KT_) * 32, (DST) + (t + 256 * i) * 8);         \
      gload_lds16(srcB[i] + (KT_) * 32, (DST) + 4096 + (t + 256 * i) * 8);  \
    } }

  GSTAGE(0, bA)
  GSTAGE(1, bB)

  f32x4 acc[4][4] = {};

  for (int kt = 0; kt < KT; ++kt) {
    // counted vmcnt: one stage (4 loads) stays in flight across the barrier
    if (kt == KT - 1) {
      asm volatile("s_waitcnt vmcnt(0)" ::: "memory");
    } else {
      asm volatile("s_waitcnt vmcnt(4)" ::: "memory");
    }
    __builtin_amdgcn_s_barrier();

    bf16x8 af[4], bfv[4];
#pragma unroll
    for (int i = 0; i < 4; ++i)
      af[i] = *reinterpret_cast<const bf16x8*>(bA + offA[i]);
#pragma unroll
    for (int j = 0; j < 4; ++j)
      bfv[j] = *reinterpret_cast<const bf16x8*>(bA + offB[j]);

#pragma unroll
    for (int i = 0; i < 4; ++i)
#pragma unroll
      for (int j = 0; j < 4; ++j)
        acc[i][j] = __builtin_amdgcn_mfma_f32_16x16x32_bf16(af[i], bfv[j], acc[i][j], 0, 0, 0);

    // prefetch tile kt+2 into the buffer whose reads completed at iter kt-1
    if (kt + 2 < KT) GSTAGE(kt + 2, bC)

    unsigned short* tmp = bA; bA = bB; bB = bC; bC = tmp;
  }
#undef GSTAGE

  // epilogue: C/D layout col = lane&15, row = (lane>>4)*4 + reg  (m89-verified)
#pragma unroll
  for (int i = 0; i < 4; ++i) {
#pragma unroll
    for (int j = 0; j < 4; ++j) {
#pragma unroll
      for (int r = 0; r < 4; ++r) {
        int m = rb * 128 + wr * 64 + i * 16 + lg * 4 + r;
        int n = cb * 128 + wc * 64 + j * 16 + lq;
        float v = acc[i][j][r];
        if (EPI == 0) {
          int which = n >> 10;
          int h = (n >> 6) & 15;
          int d = n & 63;
          int b = m >> 11;
          int tt = m & 2047;
          int bh = b * H_NUM + h;
          if (which == 0) {
            // fold softmax scale AND log2(e) so attention uses exp2 directly
            q_ws[((size_t)bh * T_SEQ + tt) * H_D + d] = f2bf(v * 0.18033688f);
          } else if (which == 1) {
            k_ws[((size_t)bh * T_SEQ + tt) * H_D + d] = f2bf(v);
          } else {
            // V transposed [BH,D,T'] with per-64-tile k-permutation matching
            // the swapped-QK^T in-register P layout (bijective bit shuffle)
            int k0 = tt & 63;
            int tp = (tt & ~63) | ((k0 & 12) << 1) | ((k0 & 48) >> 3) | (k0 & 1) | ((k0 & 2) << 4);
            v_ws[((size_t)bh * H_D + d) * T_SEQ + tp] = f2bf(v);
          }
        } else {
          outf[(size_t)m * 1024 + n] = v;
        }
      }
    }
  }
}

// ---------------------------------------------------------------- flash attention
// (unchanged -- counted-vmcnt 3-buffer pipeline, swapped QK^T in-lane softmax)
__global__ __launch_bounds__(256, 2) void attn_kernel(
    const unsigned short* __restrict__ qw,
    const unsigned short* __restrict__ kw,
    const unsigned short* __restrict__ vtw,
    unsigned short* __restrict__ yw) {
  __shared__ unsigned short kv_lds[3][8192];   // 3 bufs x (K 4096 | V 4096 shorts) = 48KB

  const int bid = blockIdx.x;
  const int bh = (bid & 7) * 8 + ((bid >> 3) & 7);
  const int qblk = bid >> 6;                    // 0..7, 256 rows each

  const int t = threadIdx.x;
  const int w = t >> 6, l = t & 63;
  const int lq = l & 15, lg = l >> 4;
  const int qbase = qblk * 256 + w * 64;
  const size_t head_off = (size_t)bh * T_SEQ * H_D;

  bf16x8 aq[4][2];
#pragma unroll
  for (int qg = 0; qg < 4; ++qg)
#pragma unroll
    for (int kk = 0; kk < 2; ++kk)
      aq[qg][kk] = *reinterpret_cast<const bf16x8*>(
          qw + head_off + (size_t)(qbase + qg * 16 + lq) * H_D + kk * 32 + lg * 8);

  const unsigned short* sbase[4];
  int sstep[4];
#pragma unroll
  for (int i = 0; i < 4; ++i) {
    int c = w * 64 + l + 256 * i;
    if (c < 512) {
      int row = c >> 3, sl = (c & 7) ^ (row & 7);
      sbase[i] = kw + head_off + row * H_D + sl * 8;
      sstep[i] = 64 * H_D;
    } else {
      int c2 = c - 512;
      int row = c2 >> 3, sl = (c2 & 7) ^ (row & 7);
      sbase[i] = vtw + head_off + (size_t)row * T_SEQ + sl * 8;
      sstep[i] = 64;
    }
  }

  unsigned short* bA = &kv_lds[0][0];
  unsigned short* bB = &kv_lds[1][0];
  unsigned short* bC = &kv_lds[2][0];

#define STAGE(KV, DST)                                                              \
  { _Pragma("unroll")                                                               \
    for (int i = 0; i < 4; ++i)                                                     \
      gload_lds16(sbase[i] + (size_t)(KV) * sstep[i], (DST) + (w * 64 + 256 * i) * 8); }

  STAGE(0, bA)
  STAGE(1, bB)

  f32x4 y[4][4] = {};
  float lrow[4] = {0.f, 0.f, 0.f, 0.f};
  union pa_t { bf16x8 v; unsigned int u[4]; };

  for (int kv = 0; kv < T_SEQ / 64; ++kv) {
    if (kv == T_SEQ / 64 - 1) {
      asm volatile("s_waitcnt vmcnt(0)" ::: "memory");
    } else {
      asm volatile("s_waitcnt vmcnt(4)" ::: "memory");
    }
    __builtin_amdgcn_s_barrier();

    bf16x8 kf[8], vf[8];
#pragma unroll
    for (int f = 0; f < 8; ++f) {
      int row = (f >> 1) * 16 + lq;
      int sl = ((f & 1) * 4 + lg) ^ (lq & 7);
      kf[f] = *reinterpret_cast<const bf16x8*>(bA + row * 64 + sl * 8);
    }
#pragma unroll
    for (int db = 0; db < 4; ++db)
#pragma unroll
      for (int ks = 0; ks < 2; ++ks) {
        int row = db * 16 + lq;
        int sl = (ks * 4 + lg) ^ (lq & 7);
        vf[db * 2 + ks] = *reinterpret_cast<const bf16x8*>(bA + 4096 + row * 64 + sl * 8);
      }

    pa_t pa0[4], pa1[4];
#pragma unroll
    for (int qg = 0; qg < 4; ++qg) {
      f32x4 s[4];
#pragma unroll
      for (int tt = 0; tt < 4; ++tt) {
        f32x4 z = {0.f, 0.f, 0.f, 0.f};
        s[tt] = __builtin_amdgcn_mfma_f32_16x16x32_bf16(kf[tt * 2], aq[qg][0], z, 0, 0, 0);
        s[tt] = __builtin_amdgcn_mfma_f32_16x16x32_bf16(kf[tt * 2 + 1], aq[qg][1], s[tt], 0, 0, 0);
      }
      float acc_e = 0.f;
#pragma unroll
      for (int tt = 0; tt < 4; ++tt) {
        float e0 = __builtin_amdgcn_exp2f(s[tt][0]);
        float e1 = __builtin_amdgcn_exp2f(s[tt][1]);
        float e2 = __builtin_amdgcn_exp2f(s[tt][2]);
        float e3 = __builtin_amdgcn_exp2f(s[tt][3]);
        pa0[qg].u[tt] = pack_hi(e0, e1);
        pa1[qg].u[tt] = pack_hi(e2, e3);
        acc_e += (e0 + e1) + (e2 + e3);
      }
      lrow[qg] += acc_e;
    }

#pragma unroll
    for (int qg = 0; qg < 4; ++qg)
#pragma unroll
      for (int db = 0; db < 4; ++db) {
        y[qg][db] = __builtin_amdgcn_mfma_f32_16x16x32_bf16(pa0[qg].v, vf[db * 2], y[qg][db], 0, 0, 0);
        y[qg][db] = __builtin_amdgcn_mfma_f32_16x16x32_bf16(pa1[qg].v, vf[db * 2 + 1], y[qg][db], 0, 0, 0);
      }

    if (kv + 2 < T_SEQ / 64) STAGE(kv + 2, bC)

    unsigned short* tmp = bA; bA = bB; bB = bC; bC = tmp;
  }
#undef STAGE

  const int b = bh >> 4, h = bh & 15;
#pragma unroll
  for (int qg = 0; qg < 4; ++qg) {
    float sm = lrow[qg];
    sm += __shfl_xor(sm, 16);
    sm += __shfl_xor(sm, 32);
    float inv = 1.0f / sm;
#pragma unroll
    for (int r = 0; r < 4; ++r) {
      float iv = __shfl(inv, lg * 4 + r);
      int row = qbase + qg * 16 + lg * 4 + r;
#pragma unroll
      for (int db = 0; db < 4; ++db) {
        int d = db * 16 + lq;
        yw[((size_t)(b * T_SEQ + row)) * C_DIM + h * 64 + d] = f2bf(y[qg][db][r] * iv);
      }
    }
  }
}

// ---------------------------------------------------------------- launch
extern "C" void kernel_launch(void* const* d_in, const int* in_sizes, int n_in,
                              void* d_out, int out_size, void* d_ws, size_t ws_size,
                              hipStream_t stream) {
  (void)in_sizes; (void)n_in; (void)out_size; (void)ws_size;
  const float* x      = (const float*)d_in[0];
  const float* w_attn = (const float*)d_in[1];
  const float* w_proj = (const float*)d_in[2];
  float* out = (float*)d_out;

  unsigned short* ws = (unsigned short*)d_ws;
  const size_t XB = (size_t)M_ROWS * C_DIM;          // 8,388,608
  unsigned short* xb  = ws;                          // x bf16 [8192,1024]; reused as y after attn
  unsigned short* wab = xb + XB;                     // w_attn bf16 [3072,1024]
  unsigned short* wpb = wab + (size_t)3072 * 1024;   // w_proj bf16 [1024,1024]
  unsigned short* qws = wpb + (size_t)1024 * 1024;   // q [BH,T,D] (pre-scaled by 0.125*log2e)
  unsigned short* kws = qws + XB;                    // k [BH,T,D]
  unsigned short* vws = kws + XB;                    // v^T [BH,D,T'] k-permuted
  unsigned short* yws = xb;                          // attention output [B,T,C] (xb dead by then)

  cast_all_kernel<<<3145728 / 256, 256, 0, stream>>>(x, w_attn, w_proj, xb, wab, wpb);

  gemm_bt_kernel<0><<<64 * 24, 256, 0, stream>>>(xb, wab, qws, kws, vws, nullptr);
  attn_kernel<<<512, 256, 0, stream>>>(qws, kws, vws, yws);
  gemm_bt_kernel<1><<<64 * 8, 256, 0, stream>>>(yws, wpb, nullptr, nullptr, nullptr, out);
}